// Round 1
// baseline (1492.462 us; speedup 1.0000x reference)
//
#include <hip/hip_runtime.h>
#include <math.h>

#define HW 9216
#define Hh 96
#define Ww 96

// ---------------------------------------------------------------------------
// Weight transpose: w[co][ci][tap] -> wt[(ci*9+tap)*Cout + co]
// Makes the 16 consecutive co weights contiguous -> uniform s_load_dwordx4.
// ---------------------------------------------------------------------------
__global__ void transpose_w_kernel(const float* __restrict__ w,
                                   float* __restrict__ wt,
                                   int Cout, int Cin) {
    int i = blockIdx.x * 256 + threadIdx.x;
    int total = Cout * Cin * 9;
    if (i >= total) return;
    int co = i / (Cin * 9);
    int r  = i - co * (Cin * 9);      // ci*9 + tap
    wt[r * Cout + co] = w[i];
}

// ---------------------------------------------------------------------------
// Generic 3x3 SAME conv, 16x16 spatial tile per block, 16 out-ch per block.
// MODE 0: plain input, leaky-relu epilogue
// MODE 1: concat(extra[192], flow1[2], flow2[2]) input, leaky-relu epilogue
// MODE 2: plain input, offset/mask epilogue (tanh*10+flow / sigmoid)
// ---------------------------------------------------------------------------
template<int CIN, int COUT, int MODE>
__launch_bounds__(256)
__global__ void conv3x3_kernel(const float* __restrict__ in0,
                               const float* __restrict__ in1,
                               const float* __restrict__ in2,
                               const float* __restrict__ wt,
                               const float* __restrict__ bias,
                               float* __restrict__ out,
                               float* __restrict__ out2,
                               const float* __restrict__ flow1,
                               const float* __restrict__ flow2) {
    constexpr int CH = 4;
    __shared__ float sm[CH * 18 * 18];
    const int tid = threadIdx.x;
    const int tx = tid & 15, ty = tid >> 4;
    const int tile = blockIdx.x;
    const int tile_y = (tile / 6) * 16, tile_x = (tile - (tile / 6) * 6) * 16;
    const int b = blockIdx.y;
    const int cob = blockIdx.z * 16;
    const int h = tile_y + ty, w = tile_x + tx;

    float acc[16];
#pragma unroll
    for (int i = 0; i < 16; ++i) acc[i] = 0.f;

    for (int c0 = 0; c0 < CIN; c0 += CH) {
        __syncthreads();
        for (int idx = tid; idx < CH * 324; idx += 256) {
            int c = idx / 324;
            int r = idx - c * 324;
            int y = r / 18, xq = r - y * 18;
            int gy = tile_y - 1 + y, gx = tile_x - 1 + xq;
            float v = 0.f;
            if (gy >= 0 && gy < Hh && gx >= 0 && gx < Ww) {
                int cg = c0 + c;
                const float* src;
                if constexpr (MODE == 1) {
                    if (cg < 192)      src = in0 + (b * 192 + cg) * HW;
                    else if (cg < 194) src = in1 + (b * 2 + (cg - 192)) * HW;
                    else               src = in2 + (b * 2 + (cg - 194)) * HW;
                } else {
                    src = in0 + (b * CIN + cg) * HW;
                }
                v = src[gy * Ww + gx];
            }
            sm[idx] = v;
        }
        __syncthreads();
#pragma unroll
        for (int c = 0; c < CH; ++c) {
#pragma unroll
            for (int t = 0; t < 9; ++t) {
                const int ky = t / 3, kx = t - ky * 3;
                float xv = sm[c * 324 + (ty + ky) * 18 + (tx + kx)];
                const float* wp = wt + ((c0 + c) * 9 + t) * COUT + cob;
#pragma unroll
                for (int co = 0; co < 16; ++co)
                    acc[co] = fmaf(wp[co], xv, acc[co]);
            }
        }
    }

    const int pix = h * Ww + w;
    if constexpr (MODE == 2) {
#pragma unroll
        for (int co = 0; co < 16; ++co) {
            int ch = cob + co;
            float v = acc[co] + bias[ch];
            if (ch < 288) {
                float t = 10.f * tanhf(v);
                const float* fl = (ch < 144) ? flow1 : flow2;
                float fv = fl[(b * 2 + (1 - (ch & 1))) * HW + pix];
                out[(b * 288 + ch) * HW + pix] = t + fv;
            } else {
                out2[(b * 144 + (ch - 288)) * HW + pix] = 1.f / (1.f + expf(-v));
            }
        }
    } else {
#pragma unroll
        for (int co = 0; co < 16; ++co) {
            float v = acc[co] + bias[cob + co];
            v = (v >= 0.f) ? v : 0.1f * v;
            out[(b * COUT + cob + co) * HW + pix] = v;
        }
    }
}

// ---------------------------------------------------------------------------
// Deformable conv: 16 groups x 8 ch/group, K=3x3, bilinear zero-pad sampling,
// mask-modulated. 16x16 spatial tile, 16 out-ch per block.
// wtd layout: [(g*8+c)*9+k][64] (same transpose as convs).
// ---------------------------------------------------------------------------
__launch_bounds__(256)
__global__ void deform_kernel(const float* __restrict__ x,
                              const float* __restrict__ offs,
                              const float* __restrict__ mask,
                              const float* __restrict__ wtd,
                              const float* __restrict__ bias,
                              float* __restrict__ out) {
    const int tid = threadIdx.x;
    const int tx = tid & 15, ty = tid >> 4;
    const int tile = blockIdx.x;
    const int tile_y = (tile / 6) * 16, tile_x = (tile - (tile / 6) * 6) * 16;
    const int b = blockIdx.y;
    const int cob = blockIdx.z * 16;
    const int h = tile_y + ty, w = tile_x + tx;
    const int pix = h * Ww + w;

    float acc[16];
#pragma unroll
    for (int i = 0; i < 16; ++i) acc[i] = 0.f;

    const float* offb = offs + b * 288 * HW + pix;
    const float* mb   = mask + b * 144 * HW + pix;

    for (int g = 0; g < 16; ++g) {
        const float* xb = x + (b * 128 + g * 8) * HW;
#pragma unroll
        for (int k = 0; k < 9; ++k) {
            const int kk = g * 9 + k;
            float dy = offb[(2 * kk) * HW];
            float dx = offb[(2 * kk + 1) * HW];
            float m  = mb[kk * HW];
            float py = dy + (float)(k / 3) + (float)h - 1.f;
            float px = dx + (float)(k % 3) + (float)w - 1.f;
            float y0f = floorf(py), x0f = floorf(px);
            float wy1 = py - y0f, wx1 = px - x0f;
            float wy0 = 1.f - wy1, wx0 = 1.f - wx1;
            int y0 = (int)y0f, x0 = (int)x0f;
            int y1 = y0 + 1, x1 = x0 + 1;
            bool vy0 = (y0 >= 0) && (y0 < Hh);
            bool vy1 = (y1 >= 0) && (y1 < Hh);
            bool vx0 = (x0 >= 0) && (x0 < Ww);
            bool vx1 = (x1 >= 0) && (x1 < Ww);
            int cy0 = min(max(y0, 0), Hh - 1), cy1 = min(max(y1, 0), Hh - 1);
            int cx0 = min(max(x0, 0), Ww - 1), cx1 = min(max(x1, 0), Ww - 1);
            float w00 = wy0 * wx0 * ((vy0 && vx0) ? m : 0.f);
            float w01 = wy0 * wx1 * ((vy0 && vx1) ? m : 0.f);
            float w10 = wy1 * wx0 * ((vy1 && vx0) ? m : 0.f);
            float w11 = wy1 * wx1 * ((vy1 && vx1) ? m : 0.f);
            int i00 = cy0 * Ww + cx0, i01 = cy0 * Ww + cx1;
            int i10 = cy1 * Ww + cx0, i11 = cy1 * Ww + cx1;
#pragma unroll
            for (int c = 0; c < 8; ++c) {
                const float* xc = xb + c * HW;
                float s = w00 * xc[i00] + w01 * xc[i01]
                        + w10 * xc[i10] + w11 * xc[i11];
                const float* wp = wtd + ((g * 8 + c) * 9 + k) * 64 + cob;
#pragma unroll
                for (int co = 0; co < 16; ++co)
                    acc[co] = fmaf(wp[co], s, acc[co]);
            }
        }
    }
#pragma unroll
    for (int co = 0; co < 16; ++co)
        out[(b * 64 + cob + co) * HW + pix] = acc[co] + bias[cob + co];
}

// ---------------------------------------------------------------------------
extern "C" void kernel_launch(void* const* d_in, const int* in_sizes, int n_in,
                              void* d_out, int out_size, void* d_ws, size_t ws_size,
                              hipStream_t stream) {
    const float* x      = (const float*)d_in[0];
    const float* extra  = (const float*)d_in[1];
    const float* flow1  = (const float*)d_in[2];
    const float* flow2  = (const float*)d_in[3];
    const float* weight = (const float*)d_in[4];
    const float* bias   = (const float*)d_in[5];
    const float* ow0    = (const float*)d_in[6];
    const float* ob0    = (const float*)d_in[7];
    const float* ow1    = (const float*)d_in[8];
    const float* ob1    = (const float*)d_in[9];
    const float* ow2    = (const float*)d_in[10];
    const float* ob2    = (const float*)d_in[11];
    const float* ow3    = (const float*)d_in[12];
    const float* ob3    = (const float*)d_in[13];
    float* out = (float*)d_out;

    float* ws  = (float*)d_ws;
    float* wt0 = ws;                        // 196*9*64 = 112896
    float* wt1 = wt0 + 196 * 9 * 64;        // 64*9*64  = 36864
    float* wt2 = wt1 + 64 * 9 * 64;
    float* wt3 = wt2 + 64 * 9 * 64;         // 64*9*432 = 248832
    float* wtd = wt3 + 64 * 9 * 432;        // 128*9*64 = 73728
    float* ha  = wtd + 128 * 9 * 64;        // 4*64*HW
    float* hb  = ha + 4 * 64 * HW;          // 4*64*HW
    float* offbuf  = hb + 4 * 64 * HW;      // 4*288*HW
    float* maskbuf = offbuf + 4 * 288 * HW; // 4*144*HW

    auto tw = [&](const float* wsrc, float* wdst, int Cout, int Cin) {
        int total = Cout * Cin * 9;
        transpose_w_kernel<<<(total + 255) / 256, 256, 0, stream>>>(wsrc, wdst, Cout, Cin);
    };
    tw(ow0, wt0, 64, 196);
    tw(ow1, wt1, 64, 64);
    tw(ow2, wt2, 64, 64);
    tw(ow3, wt3, 432, 64);
    tw(weight, wtd, 64, 128);

    dim3 blk(256);
    conv3x3_kernel<196, 64, 1><<<dim3(36, 4, 4), blk, 0, stream>>>(
        extra, flow1, flow2, wt0, ob0, ha, nullptr, nullptr, nullptr);
    conv3x3_kernel<64, 64, 0><<<dim3(36, 4, 4), blk, 0, stream>>>(
        ha, nullptr, nullptr, wt1, ob1, hb, nullptr, nullptr, nullptr);
    conv3x3_kernel<64, 64, 0><<<dim3(36, 4, 4), blk, 0, stream>>>(
        hb, nullptr, nullptr, wt2, ob2, ha, nullptr, nullptr, nullptr);
    conv3x3_kernel<64, 432, 2><<<dim3(36, 4, 27), blk, 0, stream>>>(
        ha, nullptr, nullptr, wt3, ob3, offbuf, maskbuf, flow1, flow2);
    deform_kernel<<<dim3(36, 4, 4), blk, 0, stream>>>(
        x, offbuf, maskbuf, wtd, bias, out);
}

// Round 2
// 1326.328 us; speedup vs baseline: 1.1253x; 1.1253x over previous
//
#include <hip/hip_runtime.h>
#include <math.h>

#define HW 9216
#define Hh 96
#define Ww 96

typedef __attribute__((ext_vector_type(8))) short bh8;
typedef __attribute__((ext_vector_type(4))) float f32x4;

__device__ __forceinline__ short f2bf(float f) {
    union { float f; unsigned u; } v; v.f = f;
    unsigned r = v.u + 0x7FFFu + ((v.u >> 16) & 1u);
    return (short)(r >> 16);
}

// ---------------------------------------------------------------------------
// Weight prep: w[co][k] (k = ci*9+tap) -> bf16 wb[co][Kpad], zero-padded to
// [Copad][Kpad]. Row-major in K so A-fragment loads are 16B contiguous.
// ---------------------------------------------------------------------------
__global__ void prep_w_bf16(const float* __restrict__ w, short* __restrict__ wb,
                            int Cout, int K, int Copad, int Kpad) {
    int i = blockIdx.x * 256 + threadIdx.x;
    int total = Copad * Kpad;
    if (i >= total) return;
    int co = i / Kpad, k = i - co * Kpad;
    float v = (co < Cout && k < K) ? w[co * K + k] : 0.f;
    wb[i] = f2bf(v);
}

// Deform weights stay fp32: w[co][ci][tap] -> wt[(ci*9+tap)*64 + co]
__global__ void transpose_w_kernel(const float* __restrict__ w,
                                   float* __restrict__ wt, int Cin) {
    int i = blockIdx.x * 256 + threadIdx.x;
    int total = 64 * Cin * 9;
    if (i >= total) return;
    int co = i / (Cin * 9);
    int r  = i - co * (Cin * 9);
    wt[r * 64 + co] = w[i];
}

// ---------------------------------------------------------------------------
// Implicit-GEMM conv3x3 via bf16 MFMA 16x16x32.
//   A = weights [M=cout][K], B = im2col pixels [K][N=pixel]
//   D: col(lane&15)=pixel, row(quad*4+reg)=cout  -> coalesced pixel stores
// Block: 256 thr = 4 waves; each wave 16 pixels x NT*16 couts. 64 pixels/blk.
// MODE 0: lrelu; MODE 1: concat input + lrelu; MODE 2: offset/mask epilogue.
// ---------------------------------------------------------------------------
template<int CIN, int COUT, int NT, int MODE>
__launch_bounds__(256)
__global__ void conv_mfma(const float* __restrict__ in0,
                          const float* __restrict__ in1,
                          const float* __restrict__ in2,
                          const short* __restrict__ wb,
                          const float* __restrict__ bias,
                          float* __restrict__ out,
                          float* __restrict__ out2,
                          const float* __restrict__ flow1,
                          const float* __restrict__ flow2) {
    constexpr int K   = CIN * 9;
    constexpr int KCH = (K + 31) / 32;
    constexpr int KP  = KCH * 32;
    constexpr int SMS = 40;                 // padded row stride (shorts)
    __shared__ short smA[64 * SMS];

    const int tid  = threadIdx.x;
    const int lane = tid & 63, wv = tid >> 6;
    const int q = lane >> 4, l15 = lane & 15;
    const int bx   = blockIdx.x;
    const int b    = bx / 144;
    const int pixb = (bx - b * 144) * 64;
    const int cob  = blockIdx.y * (NT * 16);

    // fill assignment: thread -> pixel fp (0..63), k-subchunk fk (0,8,16,24)
    const int fp   = tid >> 2;
    const int fk   = (tid & 3) * 8;
    const int fpix = pixb + fp;
    const int fy   = fpix / Ww;
    const int fx   = fpix - fy * Ww;

    f32x4 acc[NT];
#pragma unroll
    for (int t = 0; t < NT; ++t) acc[t] = (f32x4){0.f, 0.f, 0.f, 0.f};

    for (int kc = 0; kc < KCH; ++kc) {
        __syncthreads();
        bh8 vals;
#pragma unroll
        for (int j = 0; j < 8; ++j) {
            int k = kc * 32 + fk + j;
            float v = 0.f;
            if (k < K) {
                int ci = k / 9;
                int t9 = k - ci * 9;
                int ky = t9 / 3, kx = t9 - (t9 / 3) * 3;
                int gy = fy + ky - 1, gx = fx + kx - 1;
                if (gy >= 0 && gy < Hh && gx >= 0 && gx < Ww) {
                    const float* src;
                    if constexpr (MODE == 1) {
                        if (ci < 192)      src = in0 + (b * 192 + ci) * HW;
                        else if (ci < 194) src = in1 + (b * 2 + ci - 192) * HW;
                        else               src = in2 + (b * 2 + ci - 194) * HW;
                    } else {
                        src = in0 + (b * CIN + ci) * HW;
                    }
                    v = src[gy * Ww + gx];
                }
            }
            vals[j] = f2bf(v);
        }
        *(bh8*)&smA[fp * SMS + fk] = vals;
        __syncthreads();

        bh8 bfrag = *(const bh8*)&smA[(wv * 16 + l15) * SMS + q * 8];
        const short* wrow = wb + (cob + l15) * KP + kc * 32 + q * 8;
#pragma unroll
        for (int t = 0; t < NT; ++t) {
            bh8 afrag = *(const bh8*)(wrow + t * 16 * KP);
            acc[t] = __builtin_amdgcn_mfma_f32_16x16x32_bf16(afrag, bfrag, acc[t], 0, 0, 0);
        }
    }

    const int pix = pixb + wv * 16 + l15;
    if constexpr (MODE == 2) {
#pragma unroll
        for (int t = 0; t < NT; ++t) {
#pragma unroll
            for (int r = 0; r < 4; ++r) {
                int ch = cob + t * 16 + q * 4 + r;
                if (ch < 432) {
                    float v = acc[t][r] + bias[ch];
                    if (ch < 288) {
                        float tt = 10.f * tanhf(v);
                        const float* fl = (ch < 144) ? flow1 : flow2;
                        float fv = fl[(b * 2 + (1 - (ch & 1))) * HW + pix];
                        out[(b * 288 + ch) * HW + pix] = tt + fv;
                    } else {
                        out2[(b * 144 + (ch - 288)) * HW + pix] = 1.f / (1.f + expf(-v));
                    }
                }
            }
        }
    } else {
#pragma unroll
        for (int t = 0; t < NT; ++t) {
#pragma unroll
            for (int r = 0; r < 4; ++r) {
                int co = cob + t * 16 + q * 4 + r;
                float v = acc[t][r] + bias[co];
                v = (v >= 0.f) ? v : 0.1f * v;
                out[(b * COUT + co) * HW + pix] = v;
            }
        }
    }
}

// ---------------------------------------------------------------------------
// Deformable conv: gather ONCE per pixel, all 64 couts in registers.
// Block = 64 consecutive pixels x 256 thr (4 waves); wave w handles groups
// 4w..4w+3; LDS ds_add_f32 reduction across waves; bias added at store.
// ---------------------------------------------------------------------------
__launch_bounds__(256)
__global__ void deform_kernel(const float* __restrict__ x,
                              const float* __restrict__ offs,
                              const float* __restrict__ mask,
                              const float* __restrict__ wtd,
                              const float* __restrict__ bias,
                              float* __restrict__ out) {
    __shared__ float red[64 * 64];
    const int tid  = threadIdx.x;
    const int lane = tid & 63, wv = tid >> 6;
    const int bx   = blockIdx.x;
    const int b    = bx / 144;
    const int pixb = (bx - b * 144) * 64;
    const int pix  = pixb + lane;
    const int h    = pix / Ww;
    const int w    = pix - h * Ww;

    for (int i = tid; i < 4096; i += 256) red[i] = 0.f;
    __syncthreads();

    float acc[64];
#pragma unroll
    for (int i = 0; i < 64; ++i) acc[i] = 0.f;

    const float* offp = offs + b * 288 * HW + pix;
    const float* mp   = mask + b * 144 * HW + pix;

    for (int gi = 0; gi < 4; ++gi) {
        const int g = wv * 4 + gi;
        const float* xb = x + (b * 128 + g * 8) * HW;
#pragma unroll
        for (int k = 0; k < 9; ++k) {
            const int kk = g * 9 + k;
            float dy = offp[(2 * kk) * HW];
            float dx = offp[(2 * kk + 1) * HW];
            float m  = mp[kk * HW];
            float py = dy + (float)(k / 3) + (float)h - 1.f;
            float px = dx + (float)(k % 3) + (float)w - 1.f;
            float y0f = floorf(py), x0f = floorf(px);
            float wy1 = py - y0f, wx1 = px - x0f;
            float wy0 = 1.f - wy1, wx0 = 1.f - wx1;
            int y0 = (int)y0f, x0 = (int)x0f;
            int y1 = y0 + 1, x1 = x0 + 1;
            bool vy0 = (y0 >= 0) && (y0 < Hh);
            bool vy1 = (y1 >= 0) && (y1 < Hh);
            bool vx0 = (x0 >= 0) && (x0 < Ww);
            bool vx1 = (x1 >= 0) && (x1 < Ww);
            int cy0 = min(max(y0, 0), Hh - 1), cy1 = min(max(y1, 0), Hh - 1);
            int cx0 = min(max(x0, 0), Ww - 1), cx1 = min(max(x1, 0), Ww - 1);
            float w00 = wy0 * wx0 * ((vy0 && vx0) ? m : 0.f);
            float w01 = wy0 * wx1 * ((vy0 && vx1) ? m : 0.f);
            float w10 = wy1 * wx0 * ((vy1 && vx0) ? m : 0.f);
            float w11 = wy1 * wx1 * ((vy1 && vx1) ? m : 0.f);
            int i00 = cy0 * Ww + cx0, i01 = cy0 * Ww + cx1;
            int i10 = cy1 * Ww + cx0, i11 = cy1 * Ww + cx1;
#pragma unroll
            for (int c = 0; c < 8; ++c) {
                const float* xc = xb + c * HW;
                float s = w00 * xc[i00] + w01 * xc[i01]
                        + w10 * xc[i10] + w11 * xc[i11];
                const float* wp = wtd + ((g * 8 + c) * 9 + k) * 64;
#pragma unroll
                for (int co = 0; co < 64; ++co)
                    acc[co] = fmaf(wp[co], s, acc[co]);
            }
        }
    }

#pragma unroll
    for (int co = 0; co < 64; ++co)
        atomicAdd(&red[co * 64 + lane], acc[co]);
    __syncthreads();

    for (int i = tid; i < 4096; i += 256) {
        int co = i >> 6, pl = i & 63;
        out[(b * 64 + co) * HW + pixb + pl] = red[i] + bias[co];
    }
}

// ---------------------------------------------------------------------------
extern "C" void kernel_launch(void* const* d_in, const int* in_sizes, int n_in,
                              void* d_out, int out_size, void* d_ws, size_t ws_size,
                              hipStream_t stream) {
    const float* x      = (const float*)d_in[0];
    const float* extra  = (const float*)d_in[1];
    const float* flow1  = (const float*)d_in[2];
    const float* flow2  = (const float*)d_in[3];
    const float* weight = (const float*)d_in[4];
    const float* bias   = (const float*)d_in[5];
    const float* ow0    = (const float*)d_in[6];
    const float* ob0    = (const float*)d_in[7];
    const float* ow1    = (const float*)d_in[8];
    const float* ob1    = (const float*)d_in[9];
    const float* ow2    = (const float*)d_in[10];
    const float* ob2    = (const float*)d_in[11];
    const float* ow3    = (const float*)d_in[12];
    const float* ob3    = (const float*)d_in[13];
    float* out = (float*)d_out;

    char* wsb = (char*)d_ws;
    short* wb0 = (short*)wsb;                    wsb += 64 * 1792 * 2;
    short* wb1 = (short*)wsb;                    wsb += 64 * 576 * 2;
    short* wb2 = (short*)wsb;                    wsb += 64 * 576 * 2;
    short* wb3 = (short*)wsb;                    wsb += 448 * 576 * 2;
    float* wtd = (float*)wsb;                    wsb += 128 * 9 * 64 * 4;
    float* ha  = (float*)wsb;                    wsb += 4 * 64 * HW * 4;
    float* hb  = (float*)wsb;                    wsb += 4 * 64 * HW * 4;
    float* offbuf  = (float*)wsb;                wsb += 4 * 288 * HW * 4;
    float* maskbuf = (float*)wsb;                /* 4*144*HW*4 */

    auto grid1 = [](int n) { return dim3((n + 255) / 256); };
    prep_w_bf16<<<grid1(64 * 1792), 256, 0, stream>>>(ow0, wb0, 64, 1764, 64, 1792);
    prep_w_bf16<<<grid1(64 * 576), 256, 0, stream>>>(ow1, wb1, 64, 576, 64, 576);
    prep_w_bf16<<<grid1(64 * 576), 256, 0, stream>>>(ow2, wb2, 64, 576, 64, 576);
    prep_w_bf16<<<grid1(448 * 576), 256, 0, stream>>>(ow3, wb3, 432, 576, 448, 576);
    transpose_w_kernel<<<grid1(64 * 128 * 9), 256, 0, stream>>>(weight, wtd, 128);

    conv_mfma<196, 64, 4, 1><<<dim3(576, 1), 256, 0, stream>>>(
        extra, flow1, flow2, wb0, ob0, ha, nullptr, nullptr, nullptr);
    conv_mfma<64, 64, 4, 0><<<dim3(576, 1), 256, 0, stream>>>(
        ha, nullptr, nullptr, wb1, ob1, hb, nullptr, nullptr, nullptr);
    conv_mfma<64, 64, 4, 0><<<dim3(576, 1), 256, 0, stream>>>(
        hb, nullptr, nullptr, wb2, ob2, ha, nullptr, nullptr, nullptr);
    conv_mfma<64, 432, 7, 2><<<dim3(576, 4), 256, 0, stream>>>(
        ha, nullptr, nullptr, wb3, ob3, offbuf, maskbuf, flow1, flow2);
    deform_kernel<<<dim3(576), 256, 0, stream>>>(
        x, offbuf, maskbuf, wtd, bias, out);
}

// Round 3
// 573.014 us; speedup vs baseline: 2.6046x; 2.3147x over previous
//
#include <hip/hip_runtime.h>
#include <math.h>

#define HW 9216
#define Hh 96
#define Ww 96

typedef __attribute__((ext_vector_type(8))) short bh8;
typedef __attribute__((ext_vector_type(4))) short bh4;
typedef __attribute__((ext_vector_type(4))) float f32x4;
union bh8u { bh8 v; bh4 h[2]; };

__device__ __forceinline__ short f2bf(float f) {
    union { float f; unsigned u; } v; v.f = f;
    unsigned r = v.u + 0x7FFFu + ((v.u >> 16) & 1u);
    return (short)(r >> 16);
}
__device__ __forceinline__ float bf2f(short s) {
    union { unsigned u; float f; } v; v.u = ((unsigned)(unsigned short)s) << 16;
    return v.f;
}

// ---------------------------------------------------------------------------
// Conv weights: w[co][k] (k=ci*9+tap) -> bf16 wb[co][Kpad], zero-padded.
// ---------------------------------------------------------------------------
__global__ void prep_w_bf16(const float* __restrict__ w, short* __restrict__ wb,
                            int Cout, int K, int Copad, int Kpad) {
    int i = blockIdx.x * 256 + threadIdx.x;
    int total = Copad * Kpad;
    if (i >= total) return;
    int co = i / Kpad, k = i - co * Kpad;
    float v = (co < Cout && k < K) ? w[co * K + k] : 0.f;
    wb[i] = f2bf(v);
}

// Deform weights: reorder to k=(g*9+tap)*8+c: wbd[co][1152]
__global__ void prep_wd_bf16(const float* __restrict__ w, short* __restrict__ wbd) {
    int i = blockIdx.x * 256 + threadIdx.x;
    if (i >= 64 * 1152) return;
    int co = i / 1152, kd = i - co * 1152;
    int gt = kd >> 3, c = kd & 7;
    int g = gt / 9, tap = gt - g * 9;
    wbd[i] = f2bf(w[(co * 128 + g * 8 + c) * 9 + tap]);
}

// x NCHW -> NHWC: xt[b][pix][128]
__global__ void transpose_x(const float* __restrict__ x, float* __restrict__ xt) {
    __shared__ float t[32][33];
    const int tid = threadIdx.x;
    const int tx = tid & 31, ty = tid >> 5;
    const int pt = blockIdx.x, ct = blockIdx.y, b = blockIdx.z;
#pragma unroll
    for (int j = 0; j < 4; ++j) {
        int c = ct * 32 + ty + j * 8;
        t[ty + j * 8][tx] = x[(b * 128 + c) * HW + pt * 32 + tx];
    }
    __syncthreads();
#pragma unroll
    for (int j = 0; j < 4; ++j) {
        int pr = ty + j * 8;
        xt[((size_t)b * HW + pt * 32 + pr) * 128 + ct * 32 + tx] = t[tx][pr];
    }
}

// ---------------------------------------------------------------------------
// Implicit-GEMM conv3x3, bf16 MFMA 16x16x32. Block = 16 pixels, 4 waves,
// wave wv covers couts [wv*NT*16, ...). B-tile (im2col) shared by all waves.
// MODE 0: bf16 in, bf16 lrelu out. MODE 1: fp32 concat in, bf16 lrelu out.
// MODE 2: bf16 in, offset(fp32)/mask(bf16) epilogue.
// ---------------------------------------------------------------------------
template<int CIN, int NT, int MODE>
__launch_bounds__(256)
__global__ void conv_mfma(const void* __restrict__ in0v,
                          const float* __restrict__ in1,
                          const float* __restrict__ in2,
                          const short* __restrict__ wb,
                          const float* __restrict__ bias,
                          void* __restrict__ outv,
                          short* __restrict__ out2,
                          const float* __restrict__ flow1,
                          const float* __restrict__ flow2) {
    constexpr int K    = CIN * 9;
    constexpr int KP   = ((K + 63) / 64) * 64;
    constexpr int NPER = KP / 64;
    __shared__ __attribute__((aligned(16))) short sm[16 * 68];

    const int tid  = threadIdx.x;
    const int lane = tid & 63, wv = tid >> 6;
    const int q = lane >> 4, l15 = lane & 15;
    const int bx = blockIdx.x;
    const int b  = bx / 576;
    const int pixb = (bx - b * 576) * 16;

    const int px = tid & 15, th = tid >> 4;
    const int fpix = pixb + px;
    const int fy = fpix / Ww, fx = fpix - fy * Ww;

    f32x4 acc[NT];
#pragma unroll
    for (int t = 0; t < NT; ++t) acc[t] = (f32x4){0.f, 0.f, 0.f, 0.f};

    const short* wrowb = wb + (wv * NT * 16 + l15) * KP;

    for (int p = 0; p < NPER; ++p) {
        __syncthreads();
        bh4 vals;
#pragma unroll
        for (int j = 0; j < 4; ++j) {
            int k = p * 64 + th * 4 + j;
            short sv = 0;
            if (k < K) {
                int ci = k / 9;
                int t9 = k - ci * 9;
                int ky = t9 / 3, kx = t9 - (t9 / 3) * 3;
                int gy = fy + ky - 1, gx = fx + kx - 1;
                if (gy >= 0 && gy < Hh && gx >= 0 && gx < Ww) {
                    if constexpr (MODE == 1) {
                        const float* src;
                        if (ci < 192)      src = (const float*)in0v + (b * 192 + ci) * HW;
                        else if (ci < 194) src = in1 + (b * 2 + ci - 192) * HW;
                        else               src = in2 + (b * 2 + ci - 194) * HW;
                        sv = f2bf(src[gy * Ww + gx]);
                    } else {
                        sv = ((const short*)in0v)[(b * 64 + ci) * HW + gy * Ww + gx];
                    }
                }
            }
            vals[j] = sv;
        }
        *(bh4*)&sm[px * 68 + th * 4] = vals;
        __syncthreads();
#pragma unroll
        for (int kc = 0; kc < 2; ++kc) {
            bh8u bf;
            bf.h[0] = *(const bh4*)&sm[l15 * 68 + kc * 32 + q * 8];
            bf.h[1] = *(const bh4*)&sm[l15 * 68 + kc * 32 + q * 8 + 4];
            const short* wrow = wrowb + p * 64 + kc * 32 + q * 8;
#pragma unroll
            for (int t = 0; t < NT; ++t) {
                bh8 af = *(const bh8*)(wrow + t * 16 * KP);
                acc[t] = __builtin_amdgcn_mfma_f32_16x16x32_bf16(af, bf.v, acc[t], 0, 0, 0);
            }
        }
    }

    const int pix = pixb + l15;
    if constexpr (MODE == 2) {
        float* outo = (float*)outv;
#pragma unroll
        for (int t = 0; t < NT; ++t) {
#pragma unroll
            for (int r = 0; r < 4; ++r) {
                int ch = wv * NT * 16 + t * 16 + q * 4 + r;
                if (ch < 432) {
                    float v = acc[t][r] + bias[ch];
                    if (ch < 288) {
                        float tt = 10.f * tanhf(v);
                        const float* fl = (ch < 144) ? flow1 : flow2;
                        float fv = fl[(b * 2 + (1 - (ch & 1))) * HW + pix];
                        outo[((size_t)b * 288 + ch) * HW + pix] = tt + fv;
                    } else {
                        out2[((size_t)b * 144 + (ch - 288)) * HW + pix] =
                            f2bf(1.f / (1.f + expf(-v)));
                    }
                }
            }
        }
    } else {
        short* outs = (short*)outv;
#pragma unroll
        for (int t = 0; t < NT; ++t) {
#pragma unroll
            for (int r = 0; r < 4; ++r) {
                int co = wv * NT * 16 + t * 16 + q * 4 + r;
                float v = acc[t][r] + bias[co];
                v = (v >= 0.f) ? v : 0.1f * v;
                outs[(b * 64 + co) * HW + pix] = f2bf(v);
            }
        }
    }
}

// ---------------------------------------------------------------------------
// Deformable conv as MFMA GEMM: out[64co][pix] = W[64][1152] * S[1152][pix].
// Block = 16 pixels, 4 waves x 16 couts. Per period: 256 threads each
// bilinear-sample one (pixel, g*9+tap) -> 8 channel values (NHWC float4
// loads) -> bf16 into LDS; each wave runs 4 MFMA on the shared tile.
// ---------------------------------------------------------------------------
__launch_bounds__(256)
__global__ void deform_mfma(const float* __restrict__ xt,
                            const float* __restrict__ offs,
                            const short* __restrict__ maskb,
                            const short* __restrict__ wbd,
                            const float* __restrict__ bias,
                            float* __restrict__ out) {
    __shared__ __attribute__((aligned(16))) short sm[16 * 132];
    const int tid  = threadIdx.x;
    const int lane = tid & 63, wv = tid >> 6;
    const int q = lane >> 4, l15 = lane & 15;
    const int bx = blockIdx.x;
    const int b  = bx / 576;
    const int pixb = (bx - b * 576) * 16;

    const int px = tid & 15, gtl = tid >> 4;
    const int fpix = pixb + px;
    const int fh = fpix / Ww, fw = fpix - fh * Ww;

    const float* offp = offs + (size_t)b * 288 * HW + fpix;
    const short* mp   = maskb + (size_t)b * 144 * HW + fpix;
    const float* xb   = xt + (size_t)b * HW * 128;

    f32x4 acc = (f32x4){0.f, 0.f, 0.f, 0.f};
    const short* wrow = wbd + (wv * 16 + l15) * 1152 + q * 8;

    for (int p = 0; p < 9; ++p) {
        __syncthreads();
        const int gt = p * 16 + gtl;
        const int g = gt / 9, tap = gt - g * 9;
        float dy = offp[(size_t)(2 * gt) * HW];
        float dx = offp[(size_t)(2 * gt + 1) * HW];
        float m  = bf2f(mp[(size_t)gt * HW]);
        float py = dy + (float)(tap / 3) + (float)fh - 1.f;
        float pxx = dx + (float)(tap - (tap / 3) * 3) + (float)fw - 1.f;
        float y0f = floorf(py), x0f = floorf(pxx);
        float wy1 = py - y0f, wx1 = pxx - x0f;
        float wy0 = 1.f - wy1, wx0 = 1.f - wx1;
        int y0 = (int)y0f, x0 = (int)x0f;
        int y1 = y0 + 1, x1 = x0 + 1;
        bool vy0 = (y0 >= 0) && (y0 < Hh), vy1 = (y1 >= 0) && (y1 < Hh);
        bool vx0 = (x0 >= 0) && (x0 < Ww), vx1 = (x1 >= 0) && (x1 < Ww);
        int cy0 = min(max(y0, 0), Hh - 1), cy1 = min(max(y1, 0), Hh - 1);
        int cx0 = min(max(x0, 0), Ww - 1), cx1 = min(max(x1, 0), Ww - 1);
        float w00 = wy0 * wx0 * ((vy0 && vx0) ? m : 0.f);
        float w01 = wy0 * wx1 * ((vy0 && vx1) ? m : 0.f);
        float w10 = wy1 * wx0 * ((vy1 && vx0) ? m : 0.f);
        float w11 = wy1 * wx1 * ((vy1 && vx1) ? m : 0.f);
        const float* cb = xb + g * 8;
        const f32x4* p00 = (const f32x4*)(cb + (size_t)(cy0 * Ww + cx0) * 128);
        const f32x4* p01 = (const f32x4*)(cb + (size_t)(cy0 * Ww + cx1) * 128);
        const f32x4* p10 = (const f32x4*)(cb + (size_t)(cy1 * Ww + cx0) * 128);
        const f32x4* p11 = (const f32x4*)(cb + (size_t)(cy1 * Ww + cx1) * 128);
        f32x4 a00 = p00[0], b00 = p00[1];
        f32x4 a01 = p01[0], b01 = p01[1];
        f32x4 a10 = p10[0], b10 = p10[1];
        f32x4 a11 = p11[0], b11 = p11[1];
        bh4 o0, o1;
#pragma unroll
        for (int c = 0; c < 4; ++c) {
            float s = w00 * a00[c] + w01 * a01[c] + w10 * a10[c] + w11 * a11[c];
            o0[c] = f2bf(s);
        }
#pragma unroll
        for (int c = 0; c < 4; ++c) {
            float s = w00 * b00[c] + w01 * b01[c] + w10 * b10[c] + w11 * b11[c];
            o1[c] = f2bf(s);
        }
        *(bh4*)&sm[px * 132 + gtl * 8]     = o0;
        *(bh4*)&sm[px * 132 + gtl * 8 + 4] = o1;
        __syncthreads();
#pragma unroll
        for (int kc = 0; kc < 4; ++kc) {
            bh8u bf;
            bf.h[0] = *(const bh4*)&sm[l15 * 132 + kc * 32 + q * 8];
            bf.h[1] = *(const bh4*)&sm[l15 * 132 + kc * 32 + q * 8 + 4];
            bh8 af = *(const bh8*)(wrow + p * 128 + kc * 32);
            acc = __builtin_amdgcn_mfma_f32_16x16x32_bf16(af, bf.v, acc, 0, 0, 0);
        }
    }

    const int pix = pixb + l15;
#pragma unroll
    for (int r = 0; r < 4; ++r) {
        int co = wv * 16 + q * 4 + r;
        out[((size_t)b * 64 + co) * HW + pix] = acc[r] + bias[co];
    }
}

// ---------------------------------------------------------------------------
extern "C" void kernel_launch(void* const* d_in, const int* in_sizes, int n_in,
                              void* d_out, int out_size, void* d_ws, size_t ws_size,
                              hipStream_t stream) {
    const float* x      = (const float*)d_in[0];
    const float* extra  = (const float*)d_in[1];
    const float* flow1  = (const float*)d_in[2];
    const float* flow2  = (const float*)d_in[3];
    const float* weight = (const float*)d_in[4];
    const float* bias   = (const float*)d_in[5];
    const float* ow0    = (const float*)d_in[6];
    const float* ob0    = (const float*)d_in[7];
    const float* ow1    = (const float*)d_in[8];
    const float* ob1    = (const float*)d_in[9];
    const float* ow2    = (const float*)d_in[10];
    const float* ob2    = (const float*)d_in[11];
    const float* ow3    = (const float*)d_in[12];
    const float* ob3    = (const float*)d_in[13];
    float* out = (float*)d_out;

    float* offbuf = (float*)d_ws;                 // 4*288*HW fp32
    float* xt  = offbuf + 4 * 288 * HW;           // 4*HW*128 fp32
    short* wb0 = (short*)(xt + 4 * HW * 128);     // 64*1792
    short* wb1 = wb0 + 64 * 1792;                 // 64*576
    short* wb2 = wb1 + 64 * 576;                  // 64*576
    short* wb3 = wb2 + 64 * 576;                  // 448*576
    short* wbd = wb3 + 448 * 576;                 // 64*1152
    short* ha  = wbd + 64 * 1152;                 // 4*64*HW bf16
    short* hb  = ha + 4 * 64 * HW;                // 4*64*HW bf16
    short* maskbuf = hb + 4 * 64 * HW;            // 4*144*HW bf16

    auto g1 = [](int n) { return dim3((n + 255) / 256); };
    prep_w_bf16<<<g1(64 * 1792), 256, 0, stream>>>(ow0, wb0, 64, 1764, 64, 1792);
    prep_w_bf16<<<g1(64 * 576), 256, 0, stream>>>(ow1, wb1, 64, 576, 64, 576);
    prep_w_bf16<<<g1(64 * 576), 256, 0, stream>>>(ow2, wb2, 64, 576, 64, 576);
    prep_w_bf16<<<g1(448 * 576), 256, 0, stream>>>(ow3, wb3, 432, 576, 448, 576);
    prep_wd_bf16<<<g1(64 * 1152), 256, 0, stream>>>(weight, wbd);
    transpose_x<<<dim3(288, 4, 4), 256, 0, stream>>>(x, xt);

    conv_mfma<196, 1, 1><<<dim3(2304), 256, 0, stream>>>(
        (const void*)extra, flow1, flow2, wb0, ob0, (void*)ha, nullptr, nullptr, nullptr);
    conv_mfma<64, 1, 0><<<dim3(2304), 256, 0, stream>>>(
        (const void*)ha, nullptr, nullptr, wb1, ob1, (void*)hb, nullptr, nullptr, nullptr);
    conv_mfma<64, 1, 0><<<dim3(2304), 256, 0, stream>>>(
        (const void*)hb, nullptr, nullptr, wb2, ob2, (void*)ha, nullptr, nullptr, nullptr);
    conv_mfma<64, 7, 2><<<dim3(2304), 256, 0, stream>>>(
        (const void*)ha, nullptr, nullptr, wb3, ob3, (void*)offbuf, maskbuf, flow1, flow2);
    deform_mfma<<<dim3(2304), 256, 0, stream>>>(
        xt, offbuf, maskbuf, wbd, bias, out);
}

// Round 4
// 531.055 us; speedup vs baseline: 2.8104x; 1.0790x over previous
//
#include <hip/hip_runtime.h>
#include <math.h>

#define HW 9216
#define Hh 96
#define Ww 96
#define PHW 9604   // 98*98 padded

typedef __attribute__((ext_vector_type(8))) short bh8;
typedef __attribute__((ext_vector_type(4))) short bh4;
typedef __attribute__((ext_vector_type(4))) float f32x4;

__device__ __forceinline__ short f2bf(float f) {
    union { float f; unsigned u; } v; v.f = f;
    unsigned r = v.u + 0x7FFFu + ((v.u >> 16) & 1u);
    return (short)(r >> 16);
}
__device__ __forceinline__ float bf2f(short s) {
    union { unsigned u; float f; } v; v.u = ((unsigned)(unsigned short)s) << 16;
    return v.f;
}

// ---------------------------------------------------------------------------
__global__ void zero_ws(f32x4* __restrict__ p, int n) {
    int i = blockIdx.x * 256 + threadIdx.x;
    if (i < n) p[i] = (f32x4){0.f, 0.f, 0.f, 0.f};
}

// concat(extra,flow1,flow2) NCHW fp32 -> padded NHWC bf16 [b][98][98][224]
__global__ void pack_x1(const float* __restrict__ extra,
                        const float* __restrict__ f1,
                        const float* __restrict__ f2,
                        short* __restrict__ xp) {
    __shared__ float t[32][33];
    const int tid = threadIdx.x, tx = tid & 31, ty = tid >> 5;
    const int pt = blockIdx.x, ct = blockIdx.y, b = blockIdx.z;
#pragma unroll
    for (int j = 0; j < 4; ++j) {
        int ch = ct * 32 + ty + j * 8;
        int p = pt * 32 + tx;
        float v = 0.f;
        if (ch < 192)      v = extra[(b * 192 + ch) * HW + p];
        else if (ch < 194) v = f1[(b * 2 + ch - 192) * HW + p];
        else if (ch < 196) v = f2[(b * 2 + ch - 194) * HW + p];
        t[ty + j * 8][tx] = v;
    }
    __syncthreads();
#pragma unroll
    for (int j = 0; j < 4; ++j) {
        int pr = ty + j * 8;
        int p = pt * 32 + pr;
        int r = p / 96, c = p - r * 96;
        xp[((size_t)b * PHW + (r + 1) * 98 + (c + 1)) * 224 + ct * 32 + tx] =
            f2bf(t[tx][pr]);
    }
}

// x NCHW fp32 -> NHWC bf16 [b][9216][128]
__global__ void pack_xd(const float* __restrict__ x, short* __restrict__ xd) {
    __shared__ float t[32][33];
    const int tid = threadIdx.x, tx = tid & 31, ty = tid >> 5;
    const int pt = blockIdx.x, ct = blockIdx.y, b = blockIdx.z;
#pragma unroll
    for (int j = 0; j < 4; ++j) {
        int ch = ct * 32 + ty + j * 8;
        t[ty + j * 8][tx] = x[((size_t)b * 128 + ch) * HW + pt * 32 + tx];
    }
    __syncthreads();
#pragma unroll
    for (int j = 0; j < 4; ++j) {
        int pr = ty + j * 8;
        xd[((size_t)b * HW + pt * 32 + pr) * 128 + ct * 32 + tx] = f2bf(t[tx][pr]);
    }
}

// conv weights: w[co][cin][3][3] -> wb[co][tap][CINP] bf16, zero-padded
__global__ void prep_wconv(const float* __restrict__ w, short* __restrict__ wb,
                           int Cout, int Cin, int Copad, int CINP) {
    int i = blockIdx.x * 256 + threadIdx.x;
    int total = Copad * 9 * CINP;
    if (i >= total) return;
    int co = i / (9 * CINP);
    int r = i - co * 9 * CINP;
    int tap = r / CINP, ci = r - tap * CINP;
    float v = (co < Cout && ci < Cin) ? w[(co * Cin + ci) * 9 + tap] : 0.f;
    wb[i] = f2bf(v);
}

// deform weights: w[co][128][3][3] -> wbd[co][k=(g*9+tap)*8+c] bf16
__global__ void prep_wd(const float* __restrict__ w, short* __restrict__ wbd) {
    int i = blockIdx.x * 256 + threadIdx.x;
    if (i >= 64 * 1152) return;
    int co = i / 1152, kd = i - co * 1152;
    int gt = kd >> 3, c = kd & 7;
    int g = gt / 9, tap = gt - g * 9;
    wbd[i] = f2bf(w[(co * 128 + g * 8 + c) * 9 + tap]);
}

// ---------------------------------------------------------------------------
// Direct-global implicit-GEMM conv3x3: no LDS, no syncthreads.
// CSPLIT=2: wave = 32co x 16pix (2 pixel-tiles/block). CSPLIT=1: 64co x 16pix.
// MODE 0: lrelu -> padded NHWC bf16. MODE 2: offset/mask epilogue.
// ---------------------------------------------------------------------------
template<int CINP, int KCH, int CSPLIT, int TCO, int MODE>
__launch_bounds__(256)
__global__ void conv_mfma(const short* __restrict__ xp,
                          const short* __restrict__ wb,
                          const float* __restrict__ bias,
                          void* __restrict__ o1, short* __restrict__ o2,
                          const float* __restrict__ flow1,
                          const float* __restrict__ flow2) {
    const int tid = threadIdx.x;
    const int lane = tid & 63, wv = tid >> 6;
    const int q = lane >> 4, l15 = lane & 15;
    const int b = blockIdx.y;
    const int wv_co = (CSPLIT == 2) ? (wv & 1) : 0;
    const int wv_pt = (CSPLIT == 2) ? (wv >> 1) : wv;
    constexpr int PT = 4 / CSPLIT;
    const int pix0 = (blockIdx.x * PT + wv_pt) * 16;
    const int oh = pix0 / 96, ow = pix0 - oh * 96;
    const int co_base = blockIdx.z * 64 + wv_co * 32;

    const short* bp = xp + ((size_t)b * PHW + oh * 98 + ow + l15) * CINP + q * 8;
    const short* ap = wb + (size_t)(co_base + l15) * (9 * CINP) + q * 8;

    f32x4 acc[TCO];
#pragma unroll
    for (int t = 0; t < TCO; ++t) acc[t] = (f32x4){0.f, 0.f, 0.f, 0.f};

    for (int p = 0; p < KCH; ++p) {
#pragma unroll
        for (int tap = 0; tap < 9; ++tap) {
            const int ky = tap / 3, kx = tap - (tap / 3) * 3;
            bh8 bf = *(const bh8*)(bp + (ky * 98 + kx) * CINP + p * 32);
#pragma unroll
            for (int t = 0; t < TCO; ++t) {
                bh8 af = *(const bh8*)(ap + (size_t)t * 16 * 9 * CINP + tap * CINP + p * 32);
                acc[t] = __builtin_amdgcn_mfma_f32_16x16x32_bf16(af, bf, acc[t], 0, 0, 0);
            }
        }
    }

    const int pix = pix0 + l15;
    if constexpr (MODE == 0) {
        short* outp = (short*)o1;
        size_t base = ((size_t)b * PHW + (oh + 1) * 98 + (ow + l15 + 1)) * 64;
#pragma unroll
        for (int t = 0; t < TCO; ++t) {
            bh4 v4;
#pragma unroll
            for (int r = 0; r < 4; ++r) {
                int co = co_base + t * 16 + q * 4 + r;
                float v = acc[t][r] + bias[co];
                v = (v >= 0.f) ? v : 0.1f * v;
                v4[r] = f2bf(v);
            }
            *(bh4*)(outp + base + co_base + t * 16 + q * 4) = v4;
        }
    } else {
        float* oo = (float*)o1;
#pragma unroll
        for (int t = 0; t < TCO; ++t) {
#pragma unroll
            for (int r = 0; r < 4; ++r) {
                int ch = co_base + t * 16 + q * 4 + r;
                if (ch < 432) {
                    float v = acc[t][r] + bias[ch];
                    if (ch < 288) {
                        float tt = 10.f * tanhf(v);
                        const float* fl = (ch < 144) ? flow1 : flow2;
                        float fv = fl[(b * 2 + (1 - (ch & 1))) * HW + pix];
                        oo[((size_t)b * 288 + ch) * HW + pix] = tt + fv;
                    } else {
                        o2[((size_t)b * 144 + (ch - 288)) * HW + pix] =
                            f2bf(1.f / (1.f + expf(-v)));
                    }
                }
            }
        }
    }
}

// ---------------------------------------------------------------------------
// Deform: in-register B-fragments. Lane (l15,q) bilinear-samples
// (pix=pix0+l15, gt=wv*36+i*4+q) -> bh8 of 8 group-channels. 4 waves split
// 144 gt's; 4 MFMA per chunk (64 couts); LDS reduce across waves at end.
// ---------------------------------------------------------------------------
__launch_bounds__(256)
__global__ void deform_mfma(const short* __restrict__ xd,
                            const float* __restrict__ offs,
                            const short* __restrict__ maskb,
                            const short* __restrict__ wbd,
                            const float* __restrict__ bias,
                            float* __restrict__ out) {
    __shared__ float red[4][1024];
    const int tid = threadIdx.x;
    const int lane = tid & 63, wv = tid >> 6;
    const int q = lane >> 4, l15 = lane & 15;
    const int b = blockIdx.y;
    const int pix0 = blockIdx.x * 16;
    const int pix = pix0 + l15;
    const int h = pix / 96, w = pix - (pix / 96) * 96;

    const float* offp = offs + (size_t)b * 288 * HW + pix;
    const short* mp = maskb + (size_t)b * 144 * HW + pix;
    const short* xb = xd + (size_t)b * HW * 128;
    const short* ap = wbd + (size_t)l15 * 1152 + wv * 288 + q * 8;

    f32x4 acc[4];
#pragma unroll
    for (int t = 0; t < 4; ++t) acc[t] = (f32x4){0.f, 0.f, 0.f, 0.f};

#pragma unroll
    for (int i = 0; i < 9; ++i) {
        const int gt = wv * 36 + i * 4 + q;
        float dy = offp[(size_t)(2 * gt) * HW];
        float dx = offp[(size_t)(2 * gt + 1) * HW];
        float m  = bf2f(mp[(size_t)gt * HW]);
        int g = gt / 9, tap = gt - (gt / 9) * 9;
        float py = dy + (float)(tap / 3) + (float)h - 1.f;
        float px = dx + (float)(tap - (tap / 3) * 3) + (float)w - 1.f;
        float y0f = floorf(py), x0f = floorf(px);
        float wy1 = py - y0f, wx1 = px - x0f;
        float wy0 = 1.f - wy1, wx0 = 1.f - wx1;
        int y0 = (int)y0f, x0 = (int)x0f;
        int y1 = y0 + 1, x1 = x0 + 1;
        bool vy0 = (y0 >= 0) && (y0 < Hh), vy1 = (y1 >= 0) && (y1 < Hh);
        bool vx0 = (x0 >= 0) && (x0 < Ww), vx1 = (x1 >= 0) && (x1 < Ww);
        int cy0 = min(max(y0, 0), Hh - 1), cy1 = min(max(y1, 0), Hh - 1);
        int cx0 = min(max(x0, 0), Ww - 1), cx1 = min(max(x1, 0), Ww - 1);
        float w00 = wy0 * wx0 * ((vy0 && vx0) ? m : 0.f);
        float w01 = wy0 * wx1 * ((vy0 && vx1) ? m : 0.f);
        float w10 = wy1 * wx0 * ((vy1 && vx0) ? m : 0.f);
        float w11 = wy1 * wx1 * ((vy1 && vx1) ? m : 0.f);
        const short* cb = xb + g * 8;
        bh8 a00 = *(const bh8*)(cb + (size_t)(cy0 * 96 + cx0) * 128);
        bh8 a01 = *(const bh8*)(cb + (size_t)(cy0 * 96 + cx1) * 128);
        bh8 a10 = *(const bh8*)(cb + (size_t)(cy1 * 96 + cx0) * 128);
        bh8 a11 = *(const bh8*)(cb + (size_t)(cy1 * 96 + cx1) * 128);
        bh8 bf;
#pragma unroll
        for (int c = 0; c < 8; ++c) {
            float s = w00 * bf2f(a00[c]) + w01 * bf2f(a01[c])
                    + w10 * bf2f(a10[c]) + w11 * bf2f(a11[c]);
            bf[c] = f2bf(s);
        }
#pragma unroll
        for (int t = 0; t < 4; ++t) {
            bh8 af = *(const bh8*)(ap + (size_t)t * 16 * 1152 + i * 32);
            acc[t] = __builtin_amdgcn_mfma_f32_16x16x32_bf16(af, bf, acc[t], 0, 0, 0);
        }
    }

#pragma unroll
    for (int t = 0; t < 4; ++t)
#pragma unroll
        for (int r = 0; r < 4; ++r)
            red[wv][(t * 16 + q * 4 + r) * 16 + l15] = acc[t][r];
    __syncthreads();
    for (int e = tid; e < 1024; e += 256) {
        int co = e >> 4, pl = e & 15;
        float v = red[0][e] + red[1][e] + red[2][e] + red[3][e] + bias[co];
        out[((size_t)b * 64 + co) * HW + pix0 + pl] = v;
    }
}

// ---------------------------------------------------------------------------
extern "C" void kernel_launch(void* const* d_in, const int* in_sizes, int n_in,
                              void* d_out, int out_size, void* d_ws, size_t ws_size,
                              hipStream_t stream) {
    const float* x      = (const float*)d_in[0];
    const float* extra  = (const float*)d_in[1];
    const float* flow1  = (const float*)d_in[2];
    const float* flow2  = (const float*)d_in[3];
    const float* weight = (const float*)d_in[4];
    const float* bias   = (const float*)d_in[5];
    const float* ow0    = (const float*)d_in[6];
    const float* ob0    = (const float*)d_in[7];
    const float* ow1    = (const float*)d_in[8];
    const float* ob1    = (const float*)d_in[9];
    const float* ow2    = (const float*)d_in[10];
    const float* ob2    = (const float*)d_in[11];
    const float* ow3    = (const float*)d_in[12];
    const float* ob3    = (const float*)d_in[13];
    float* out = (float*)d_out;

    char* wsb = (char*)d_ws;
    short* xpad1 = (short*)wsb;   wsb += (size_t)4 * PHW * 224 * 2;  // zeroed
    short* hpa   = (short*)wsb;   wsb += (size_t)4 * PHW * 64 * 2;   // zeroed
    short* hpb   = (short*)wsb;   wsb += (size_t)4 * PHW * 64 * 2;   // zeroed
    size_t zbytes = (char*)wsb - (char*)d_ws;
    float* offbuf  = (float*)wsb; wsb += (size_t)4 * 288 * HW * 4;
    short* maskbuf = (short*)wsb; wsb += (size_t)4 * 144 * HW * 2;
    short* xd      = (short*)wsb; wsb += (size_t)4 * HW * 128 * 2;
    short* wb0     = (short*)wsb; wsb += 64 * 9 * 224 * 2;
    short* wb1     = (short*)wsb; wsb += 64 * 9 * 64 * 2;
    short* wb2     = (short*)wsb; wsb += 64 * 9 * 64 * 2;
    short* wb3     = (short*)wsb; wsb += 448 * 9 * 64 * 2;
    short* wbd     = (short*)wsb;

    auto g1 = [](int n) { return dim3((n + 255) / 256); };
    int zn = (int)(zbytes / 16);
    zero_ws<<<g1(zn), 256, 0, stream>>>((f32x4*)d_ws, zn);
    pack_x1<<<dim3(288, 7, 4), 256, 0, stream>>>(extra, flow1, flow2, xpad1);
    pack_xd<<<dim3(288, 4, 4), 256, 0, stream>>>(x, xd);
    prep_wconv<<<g1(64 * 9 * 224), 256, 0, stream>>>(ow0, wb0, 64, 196, 64, 224);
    prep_wconv<<<g1(64 * 9 * 64), 256, 0, stream>>>(ow1, wb1, 64, 64, 64, 64);
    prep_wconv<<<g1(64 * 9 * 64), 256, 0, stream>>>(ow2, wb2, 64, 64, 64, 64);
    prep_wconv<<<g1(448 * 9 * 64), 256, 0, stream>>>(ow3, wb3, 432, 64, 448, 64);
    prep_wd<<<g1(64 * 1152), 256, 0, stream>>>(weight, wbd);

    conv_mfma<224, 7, 2, 2, 0><<<dim3(288, 4, 1), 256, 0, stream>>>(
        xpad1, wb0, ob0, (void*)hpa, nullptr, nullptr, nullptr);
    conv_mfma<64, 2, 2, 2, 0><<<dim3(288, 4, 1), 256, 0, stream>>>(
        hpa, wb1, ob1, (void*)hpb, nullptr, nullptr, nullptr);
    conv_mfma<64, 2, 2, 2, 0><<<dim3(288, 4, 1), 256, 0, stream>>>(
        hpb, wb2, ob2, (void*)hpa, nullptr, nullptr, nullptr);
    conv_mfma<64, 2, 1, 4, 2><<<dim3(144, 4, 7), 256, 0, stream>>>(
        hpa, wb3, ob3, (void*)offbuf, maskbuf, flow1, flow2);
    deform_mfma<<<dim3(576, 4), 256, 0, stream>>>(
        xd, offbuf, maskbuf, wbd, bias, out);
}

// Round 5
// 336.849 us; speedup vs baseline: 4.4307x; 1.5765x over previous
//
#include <hip/hip_runtime.h>
#include <math.h>

#define HW 9216
#define Hh 96
#define Ww 96
#define PHW 9604   // 98*98 padded

typedef __attribute__((ext_vector_type(8))) short bh8;
typedef __attribute__((ext_vector_type(4))) short bh4;
typedef __attribute__((ext_vector_type(4))) float f32x4;

__device__ __forceinline__ short f2bf(float f) {
    union { float f; unsigned u; } v; v.f = f;
    unsigned r = v.u + 0x7FFFu + ((v.u >> 16) & 1u);
    return (short)(r >> 16);
}
__device__ __forceinline__ float bf2f(short s) {
    union { unsigned u; float f; } v; v.u = ((unsigned)(unsigned short)s) << 16;
    return v.f;
}

// ---------------------------------------------------------------------------
// Zero only the pad border (interior is fully overwritten every call).
__global__ void zero_border(short* __restrict__ p, int C) {
    int i = blockIdx.x * 256 + threadIdx.x;
    int total = 4 * 388 * C;
    if (i >= total) return;
    int c = i % C;
    int r = i / C;
    int b = r / 388, pid = r - b * 388;
    int row, col;
    if (pid < 98)       { row = 0;  col = pid; }
    else if (pid < 196) { row = 97; col = pid - 98; }
    else if (pid < 292) { row = pid - 196 + 1; col = 0; }
    else                { row = pid - 292 + 1; col = 97; }
    p[((size_t)b * PHW + row * 98 + col) * C + c] = 0;
}

// concat(extra,flow1,flow2) NCHW fp32 -> padded NHWC bf16 [b][98][98][224]
__global__ void pack_x1(const float* __restrict__ extra,
                        const float* __restrict__ f1,
                        const float* __restrict__ f2,
                        short* __restrict__ xp) {
    __shared__ float t[32][33];
    const int tid = threadIdx.x, tx = tid & 31, ty = tid >> 5;
    const int pt = blockIdx.x, ct = blockIdx.y, b = blockIdx.z;
#pragma unroll
    for (int j = 0; j < 4; ++j) {
        int ch = ct * 32 + ty + j * 8;
        int p = pt * 32 + tx;
        float v = 0.f;
        if (ch < 192)      v = extra[(b * 192 + ch) * HW + p];
        else if (ch < 194) v = f1[(b * 2 + ch - 192) * HW + p];
        else if (ch < 196) v = f2[(b * 2 + ch - 194) * HW + p];
        t[ty + j * 8][tx] = v;
    }
    __syncthreads();
#pragma unroll
    for (int j = 0; j < 4; ++j) {
        int pr = ty + j * 8;
        int p = pt * 32 + pr;
        int r = p / 96, c = p - r * 96;
        xp[((size_t)b * PHW + (r + 1) * 98 + (c + 1)) * 224 + ct * 32 + tx] =
            f2bf(t[tx][pr]);
    }
}

// x NCHW fp32 -> NHWC bf16 [b][9216][128]
__global__ void pack_xd(const float* __restrict__ x, short* __restrict__ xd) {
    __shared__ float t[32][33];
    const int tid = threadIdx.x, tx = tid & 31, ty = tid >> 5;
    const int pt = blockIdx.x, ct = blockIdx.y, b = blockIdx.z;
#pragma unroll
    for (int j = 0; j < 4; ++j) {
        int ch = ct * 32 + ty + j * 8;
        t[ty + j * 8][tx] = x[((size_t)b * 128 + ch) * HW + pt * 32 + tx];
    }
    __syncthreads();
#pragma unroll
    for (int j = 0; j < 4; ++j) {
        int pr = ty + j * 8;
        xd[((size_t)b * HW + pt * 32 + pr) * 128 + ct * 32 + tx] = f2bf(t[tx][pr]);
    }
}

// conv weights: w[co][cin][3][3] -> wb[co][tap][CINP] bf16, zero-padded
__global__ void prep_wconv(const float* __restrict__ w, short* __restrict__ wb,
                           int Cout, int Cin, int Copad, int CINP) {
    int i = blockIdx.x * 256 + threadIdx.x;
    int total = Copad * 9 * CINP;
    if (i >= total) return;
    int co = i / (9 * CINP);
    int r = i - co * 9 * CINP;
    int tap = r / CINP, ci = r - tap * CINP;
    float v = (co < Cout && ci < Cin) ? w[(co * Cin + ci) * 9 + tap] : 0.f;
    wb[i] = f2bf(v);
}

// deform weights: w[co][128][3][3] -> wbd[co][k=(g*9+tap)*8+c] bf16
__global__ void prep_wd(const float* __restrict__ w, short* __restrict__ wbd) {
    int i = blockIdx.x * 256 + threadIdx.x;
    if (i >= 64 * 1152) return;
    int co = i / 1152, kd = i - co * 1152;
    int gt = kd >> 3, c = kd & 7;
    int g = gt / 9, tap = gt - g * 9;
    wbd[i] = f2bf(w[(co * 128 + g * 8 + c) * 9 + tap]);
}

// ---------------------------------------------------------------------------
// Implicit-GEMM conv3x3, bf16 MFMA 16x16x32.
// Block = 4 waves, 64 couts. Weights for the current 32-cin K-chunk staged in
// LDS [tap][64co][32ci] (36.9 KB) by all threads; each wave handles PIX
// 16-pixel strips (B-frags direct 16B global loads from padded NHWC input).
// Per tap: PIX B-loads + 4 ds_read_b128 A-frags + 4*PIX MFMA.
// MODE 0: lrelu -> padded NHWC bf16. MODE 2: offset/mask epilogue.
// ---------------------------------------------------------------------------
template<int CINP, int KCH, int PIX, int MODE>
__launch_bounds__(256)
__global__ void conv_mfma(const short* __restrict__ xp,
                          const short* __restrict__ wb,
                          const float* __restrict__ bias,
                          void* __restrict__ o1, short* __restrict__ o2,
                          const float* __restrict__ flow1,
                          const float* __restrict__ flow2) {
    __shared__ __attribute__((aligned(16))) short smA[9 * 64 * 32];
    const int tid = threadIdx.x;
    const int lane = tid & 63, wv = tid >> 6;
    const int q = lane >> 4, l15 = lane & 15;
    const int b = blockIdx.y;
    const int co_base = blockIdx.z * 64;
    const int pix0 = blockIdx.x * (64 * PIX) + wv * (16 * PIX);

    int soh[PIX], sow[PIX];
    const short* bp[PIX];
#pragma unroll
    for (int s = 0; s < PIX; ++s) {
        int pixs = pix0 + s * 16;
        soh[s] = pixs / 96;
        sow[s] = pixs - soh[s] * 96;
        bp[s] = xp + ((size_t)b * PHW + soh[s] * 98 + sow[s] + l15) * CINP + q * 8;
    }

    const int sco = tid >> 2, sqq = tid & 3;   // staging role
    const short* wsrc = wb + (size_t)(co_base + sco) * (9 * CINP) + sqq * 8;

    f32x4 acc[PIX][4];
#pragma unroll
    for (int s = 0; s < PIX; ++s)
#pragma unroll
        for (int t = 0; t < 4; ++t) acc[s][t] = (f32x4){0.f, 0.f, 0.f, 0.f};

    for (int p = 0; p < KCH; ++p) {
        __syncthreads();
        bh8 wtmp[9];
#pragma unroll
        for (int tap = 0; tap < 9; ++tap)
            wtmp[tap] = *(const bh8*)(wsrc + tap * CINP + p * 32);
#pragma unroll
        for (int tap = 0; tap < 9; ++tap)
            *(bh8*)&smA[tap * 2048 + sco * 32 + sqq * 8] = wtmp[tap];
        __syncthreads();
#pragma unroll
        for (int tap = 0; tap < 9; ++tap) {
            const int ky = tap / 3, kx = tap - (tap / 3) * 3;
            bh8 bf[PIX];
#pragma unroll
            for (int s = 0; s < PIX; ++s)
                bf[s] = *(const bh8*)(bp[s] + (ky * 98 + kx) * CINP + p * 32);
#pragma unroll
            for (int t = 0; t < 4; ++t) {
                bh8 af = *(const bh8*)&smA[tap * 2048 + (t * 16 + l15) * 32 + q * 8];
#pragma unroll
                for (int s = 0; s < PIX; ++s)
                    acc[s][t] = __builtin_amdgcn_mfma_f32_16x16x32_bf16(
                        af, bf[s], acc[s][t], 0, 0, 0);
            }
        }
    }

#pragma unroll
    for (int s = 0; s < PIX; ++s) {
        const int pix = pix0 + s * 16 + l15;
        if constexpr (MODE == 0) {
            short* outp = (short*)o1;
            size_t base = ((size_t)b * PHW + (soh[s] + 1) * 98 + sow[s] + l15 + 1) * 64;
#pragma unroll
            for (int t = 0; t < 4; ++t) {
                bh4 v4;
#pragma unroll
                for (int r = 0; r < 4; ++r) {
                    int co = co_base + t * 16 + q * 4 + r;
                    float v = acc[s][t][r] + bias[co];
                    v = (v >= 0.f) ? v : 0.1f * v;
                    v4[r] = f2bf(v);
                }
                *(bh4*)(outp + base + t * 16 + q * 4) = v4;
            }
        } else {
            float* oo = (float*)o1;
#pragma unroll
            for (int t = 0; t < 4; ++t) {
#pragma unroll
                for (int r = 0; r < 4; ++r) {
                    int ch = co_base + t * 16 + q * 4 + r;
                    if (ch < 432) {
                        float v = acc[s][t][r] + bias[ch];
                        if (ch < 288) {
                            float tt = 10.f * tanhf(v);
                            const float* fl = (ch < 144) ? flow1 : flow2;
                            float fv = fl[(b * 2 + (1 - (ch & 1))) * HW + pix];
                            oo[((size_t)b * 288 + ch) * HW + pix] = tt + fv;
                        } else {
                            o2[((size_t)b * 144 + (ch - 288)) * HW + pix] =
                                f2bf(1.f / (1.f + expf(-v)));
                        }
                    }
                }
            }
        }
    }
}

// ---------------------------------------------------------------------------
// Deform: in-register B-fragments. Lane (l15,q) bilinear-samples
// (pix=pix0+l15, gt=wv*36+i*4+q) -> bh8 of 8 group-channels. 4 waves split
// 144 gt's; 4 MFMA per chunk (64 couts); LDS reduce across waves at end.
// ---------------------------------------------------------------------------
__launch_bounds__(256)
__global__ void deform_mfma(const short* __restrict__ xd,
                            const float* __restrict__ offs,
                            const short* __restrict__ maskb,
                            const short* __restrict__ wbd,
                            const float* __restrict__ bias,
                            float* __restrict__ out) {
    __shared__ float red[4][1024];
    const int tid = threadIdx.x;
    const int lane = tid & 63, wv = tid >> 6;
    const int q = lane >> 4, l15 = lane & 15;
    const int b = blockIdx.y;
    const int pix0 = blockIdx.x * 16;
    const int pix = pix0 + l15;
    const int h = pix / 96, w = pix - (pix / 96) * 96;

    const float* offp = offs + (size_t)b * 288 * HW + pix;
    const short* mp = maskb + (size_t)b * 144 * HW + pix;
    const short* xb = xd + (size_t)b * HW * 128;
    const short* ap = wbd + (size_t)l15 * 1152 + wv * 288 + q * 8;

    f32x4 acc[4];
#pragma unroll
    for (int t = 0; t < 4; ++t) acc[t] = (f32x4){0.f, 0.f, 0.f, 0.f};

#pragma unroll
    for (int i = 0; i < 9; ++i) {
        const int gt = wv * 36 + i * 4 + q;
        float dy = offp[(size_t)(2 * gt) * HW];
        float dx = offp[(size_t)(2 * gt + 1) * HW];
        float m  = bf2f(mp[(size_t)gt * HW]);
        int g = gt / 9, tap = gt - (gt / 9) * 9;
        float py = dy + (float)(tap / 3) + (float)h - 1.f;
        float px = dx + (float)(tap - (tap / 3) * 3) + (float)w - 1.f;
        float y0f = floorf(py), x0f = floorf(px);
        float wy1 = py - y0f, wx1 = px - x0f;
        float wy0 = 1.f - wy1, wx0 = 1.f - wx1;
        int y0 = (int)y0f, x0 = (int)x0f;
        int y1 = y0 + 1, x1 = x0 + 1;
        bool vy0 = (y0 >= 0) && (y0 < Hh), vy1 = (y1 >= 0) && (y1 < Hh);
        bool vx0 = (x0 >= 0) && (x0 < Ww), vx1 = (x1 >= 0) && (x1 < Ww);
        int cy0 = min(max(y0, 0), Hh - 1), cy1 = min(max(y1, 0), Hh - 1);
        int cx0 = min(max(x0, 0), Ww - 1), cx1 = min(max(x1, 0), Ww - 1);
        float w00 = wy0 * wx0 * ((vy0 && vx0) ? m : 0.f);
        float w01 = wy0 * wx1 * ((vy0 && vx1) ? m : 0.f);
        float w10 = wy1 * wx0 * ((vy1 && vx0) ? m : 0.f);
        float w11 = wy1 * wx1 * ((vy1 && vx1) ? m : 0.f);
        const short* cb = xb + g * 8;
        bh8 a00 = *(const bh8*)(cb + (size_t)(cy0 * 96 + cx0) * 128);
        bh8 a01 = *(const bh8*)(cb + (size_t)(cy0 * 96 + cx1) * 128);
        bh8 a10 = *(const bh8*)(cb + (size_t)(cy1 * 96 + cx0) * 128);
        bh8 a11 = *(const bh8*)(cb + (size_t)(cy1 * 96 + cx1) * 128);
        bh8 bf;
#pragma unroll
        for (int c = 0; c < 8; ++c) {
            float s = w00 * bf2f(a00[c]) + w01 * bf2f(a01[c])
                    + w10 * bf2f(a10[c]) + w11 * bf2f(a11[c]);
            bf[c] = f2bf(s);
        }
#pragma unroll
        for (int t = 0; t < 4; ++t) {
            bh8 af = *(const bh8*)(ap + (size_t)t * 16 * 1152 + i * 32);
            acc[t] = __builtin_amdgcn_mfma_f32_16x16x32_bf16(af, bf, acc[t], 0, 0, 0);
        }
    }

#pragma unroll
    for (int t = 0; t < 4; ++t)
#pragma unroll
        for (int r = 0; r < 4; ++r)
            red[wv][(t * 16 + q * 4 + r) * 16 + l15] = acc[t][r];
    __syncthreads();
    for (int e = tid; e < 1024; e += 256) {
        int co = e >> 4, pl = e & 15;
        float v = red[0][e] + red[1][e] + red[2][e] + red[3][e] + bias[co];
        out[((size_t)b * 64 + co) * HW + pix0 + pl] = v;
    }
}

// ---------------------------------------------------------------------------
extern "C" void kernel_launch(void* const* d_in, const int* in_sizes, int n_in,
                              void* d_out, int out_size, void* d_ws, size_t ws_size,
                              hipStream_t stream) {
    const float* x      = (const float*)d_in[0];
    const float* extra  = (const float*)d_in[1];
    const float* flow1  = (const float*)d_in[2];
    const float* flow2  = (const float*)d_in[3];
    const float* weight = (const float*)d_in[4];
    const float* bias   = (const float*)d_in[5];
    const float* ow0    = (const float*)d_in[6];
    const float* ob0    = (const float*)d_in[7];
    const float* ow1    = (const float*)d_in[8];
    const float* ob1    = (const float*)d_in[9];
    const float* ow2    = (const float*)d_in[10];
    const float* ob2    = (const float*)d_in[11];
    const float* ow3    = (const float*)d_in[12];
    const float* ob3    = (const float*)d_in[13];
    float* out = (float*)d_out;

    char* wsb = (char*)d_ws;
    short* xpad1 = (short*)wsb;   wsb += (size_t)4 * PHW * 224 * 2;
    short* hpa   = (short*)wsb;   wsb += (size_t)4 * PHW * 64 * 2;
    short* hpb   = (short*)wsb;   wsb += (size_t)4 * PHW * 64 * 2;
    float* offbuf  = (float*)wsb; wsb += (size_t)4 * 288 * HW * 4;
    short* maskbuf = (short*)wsb; wsb += (size_t)4 * 144 * HW * 2;
    short* xd      = (short*)wsb; wsb += (size_t)4 * HW * 128 * 2;
    short* wb0     = (short*)wsb; wsb += 64 * 9 * 224 * 2;
    short* wb1     = (short*)wsb; wsb += 64 * 9 * 64 * 2;
    short* wb2     = (short*)wsb; wsb += 64 * 9 * 64 * 2;
    short* wb3     = (short*)wsb; wsb += 448 * 9 * 64 * 2;
    short* wbd     = (short*)wsb;

    auto g1 = [](int n) { return dim3((n + 255) / 256); };
    zero_border<<<g1(4 * 388 * 224), 256, 0, stream>>>(xpad1, 224);
    zero_border<<<g1(4 * 388 * 64), 256, 0, stream>>>(hpa, 64);
    zero_border<<<g1(4 * 388 * 64), 256, 0, stream>>>(hpb, 64);
    pack_x1<<<dim3(288, 7, 4), 256, 0, stream>>>(extra, flow1, flow2, xpad1);
    pack_xd<<<dim3(288, 4, 4), 256, 0, stream>>>(x, xd);
    prep_wconv<<<g1(64 * 9 * 224), 256, 0, stream>>>(ow0, wb0, 64, 196, 64, 224);
    prep_wconv<<<g1(64 * 9 * 64), 256, 0, stream>>>(ow1, wb1, 64, 64, 64, 64);
    prep_wconv<<<g1(64 * 9 * 64), 256, 0, stream>>>(ow2, wb2, 64, 64, 64, 64);
    prep_wconv<<<g1(448 * 9 * 64), 256, 0, stream>>>(ow3, wb3, 432, 64, 448, 64);
    prep_wd<<<g1(64 * 1152), 256, 0, stream>>>(weight, wbd);

    conv_mfma<224, 7, 1, 0><<<dim3(144, 4, 1), 256, 0, stream>>>(
        xpad1, wb0, ob0, (void*)hpa, nullptr, nullptr, nullptr);
    conv_mfma<64, 2, 1, 0><<<dim3(144, 4, 1), 256, 0, stream>>>(
        hpa, wb1, ob1, (void*)hpb, nullptr, nullptr, nullptr);
    conv_mfma<64, 2, 1, 0><<<dim3(144, 4, 1), 256, 0, stream>>>(
        hpb, wb2, ob2, (void*)hpa, nullptr, nullptr, nullptr);
    conv_mfma<64, 2, 2, 2><<<dim3(72, 4, 7), 256, 0, stream>>>(
        hpa, wb3, ob3, (void*)offbuf, maskbuf, flow1, flow2);
    deform_mfma<<<dim3(576, 4), 256, 0, stream>>>(
        xd, offbuf, maskbuf, wbd, bias, out);
}

// Round 6
// 314.837 us; speedup vs baseline: 4.7404x; 1.0699x over previous
//
#include <hip/hip_runtime.h>
#include <math.h>

#define HW 9216
#define Hh 96
#define Ww 96
#define PHW 9604   // 98*98 padded

typedef __attribute__((ext_vector_type(8))) short bh8;
typedef __attribute__((ext_vector_type(4))) short bh4;
typedef __attribute__((ext_vector_type(4))) float f32x4;
typedef __attribute__((ext_vector_type(2))) float f32x2;

__device__ __forceinline__ short f2bf(float f) {
    union { float f; unsigned u; } v; v.f = f;
    unsigned r = v.u + 0x7FFFu + ((v.u >> 16) & 1u);
    return (short)(r >> 16);
}
__device__ __forceinline__ float bf2f(short s) {
    union { unsigned u; float f; } v; v.u = ((unsigned)(unsigned short)s) << 16;
    return v.f;
}

// ---------------------------------------------------------------------------
// Fused: zero pad borders of xpad1 (224ch), hpa (64ch), hpb (64ch).
__global__ void zero_borders(short* __restrict__ xpad1,
                             short* __restrict__ hpa,
                             short* __restrict__ hpb) {
    int i = blockIdx.x * 256 + threadIdx.x;
    const int n1 = 4 * 388 * 224, n2 = 4 * 388 * 64;
    short* p; int C;
    if (i < n1) { p = xpad1; C = 224; }
    else if (i < n1 + n2) { p = hpa; C = 64; i -= n1; }
    else if (i < n1 + 2 * n2) { p = hpb; C = 64; i -= n1 + n2; }
    else return;
    int c = i % C;
    int r = i / C;
    int b = r / 388, pid = r - b * 388;
    int row, col;
    if (pid < 98)       { row = 0;  col = pid; }
    else if (pid < 196) { row = 97; col = pid - 98; }
    else if (pid < 292) { row = pid - 196 + 1; col = 0; }
    else                { row = pid - 292 + 1; col = 97; }
    p[((size_t)b * PHW + row * 98 + col) * C + c] = 0;
}

// concat(extra,flow1,flow2) NCHW fp32 -> padded NHWC bf16 [b][98][98][224]
__global__ void pack_x1(const float* __restrict__ extra,
                        const float* __restrict__ f1,
                        const float* __restrict__ f2,
                        short* __restrict__ xp) {
    __shared__ float t[32][33];
    const int tid = threadIdx.x, tx = tid & 31, ty = tid >> 5;
    const int pt = blockIdx.x, ct = blockIdx.y, b = blockIdx.z;
#pragma unroll
    for (int j = 0; j < 4; ++j) {
        int ch = ct * 32 + ty + j * 8;
        int p = pt * 32 + tx;
        float v = 0.f;
        if (ch < 192)      v = extra[(b * 192 + ch) * HW + p];
        else if (ch < 194) v = f1[(b * 2 + ch - 192) * HW + p];
        else if (ch < 196) v = f2[(b * 2 + ch - 194) * HW + p];
        t[ty + j * 8][tx] = v;
    }
    __syncthreads();
#pragma unroll
    for (int j = 0; j < 4; ++j) {
        int pr = ty + j * 8;
        int p = pt * 32 + pr;
        int r = p / 96, c = p - r * 96;
        xp[((size_t)b * PHW + (r + 1) * 98 + (c + 1)) * 224 + ct * 32 + tx] =
            f2bf(t[tx][pr]);
    }
}

// x NCHW fp32 -> [b][16g][9216pix][8ch] bf16 (group-planar for deform gathers)
__global__ void pack_xd(const float* __restrict__ x, short* __restrict__ xd) {
    __shared__ float t[32][33];
    const int tid = threadIdx.x, tx = tid & 31, ty = tid >> 5;
    const int pt = blockIdx.x, ct = blockIdx.y, b = blockIdx.z;
#pragma unroll
    for (int j = 0; j < 4; ++j) {
        int ch = ct * 32 + ty + j * 8;
        t[ty + j * 8][tx] = x[((size_t)b * 128 + ch) * HW + pt * 32 + tx];
    }
    __syncthreads();
    if (tid < 128) {
        int oct = tid >> 5, p = tid & 31;
        int g = (ct * 32 + oct * 8) >> 3;
        bh8 v;
#pragma unroll
        for (int c = 0; c < 8; ++c) v[c] = f2bf(t[oct * 8 + c][p]);
        *(bh8*)&xd[(((size_t)b * 16 + g) * HW + pt * 32 + p) * 8] = v;
    }
}

// ---------------------------------------------------------------------------
// Fused weight prep: all conv weights -> bf16 [co][tap][cinP]; deform -> [co][1152]
__global__ void prep_weights(const float* __restrict__ ow0, const float* __restrict__ ow1,
                             const float* __restrict__ ow2, const float* __restrict__ ow3,
                             const float* __restrict__ wd,
                             short* __restrict__ wb0, short* __restrict__ wb1,
                             short* __restrict__ wb2, short* __restrict__ wb3,
                             short* __restrict__ wbd) {
    int i = blockIdx.x * 256 + threadIdx.x;
    const int n0 = 64 * 9 * 224, n1 = 64 * 9 * 64, n3 = 448 * 9 * 64, nd = 64 * 1152;
    if (i < n0) {
        int co = i / (9 * 224); int r = i - co * (9 * 224);
        int tap = r / 224, ci = r - tap * 224;
        wb0[i] = f2bf(ci < 196 ? ow0[(co * 196 + ci) * 9 + tap] : 0.f);
        return;
    }
    i -= n0;
    if (i < n1) {
        int co = i / (9 * 64); int r = i - co * (9 * 64);
        int tap = r / 64, ci = r - tap * 64;
        wb1[i] = f2bf(ow1[(co * 64 + ci) * 9 + tap]);
        return;
    }
    i -= n1;
    if (i < n1) {
        int co = i / (9 * 64); int r = i - co * (9 * 64);
        int tap = r / 64, ci = r - tap * 64;
        wb2[i] = f2bf(ow2[(co * 64 + ci) * 9 + tap]);
        return;
    }
    i -= n1;
    if (i < n3) {
        int co = i / (9 * 64); int r = i - co * (9 * 64);
        int tap = r / 64, ci = r - tap * 64;
        wb3[i] = f2bf(co < 432 ? ow3[(co * 64 + ci) * 9 + tap] : 0.f);
        return;
    }
    i -= n3;
    if (i < nd) {
        int co = i / 1152, kd = i - co * 1152;
        int gt = kd >> 3, c = kd & 7;
        int g = gt / 9, tap = gt - g * 9;
        wbd[i] = f2bf(wd[(co * 128 + g * 8 + c) * 9 + tap]);
    }
}

// ---------------------------------------------------------------------------
// conv1-3: chunked-weight implicit GEMM (round-5 structure, MODE 0 only).
// ---------------------------------------------------------------------------
template<int CINP, int KCH, int PIX>
__launch_bounds__(256)
__global__ void conv_mfma(const short* __restrict__ xp,
                          const short* __restrict__ wb,
                          const float* __restrict__ bias,
                          short* __restrict__ o1) {
    __shared__ __attribute__((aligned(16))) short smA[9 * 64 * 32];
    const int tid = threadIdx.x;
    const int lane = tid & 63, wv = tid >> 6;
    const int q = lane >> 4, l15 = lane & 15;
    const int b = blockIdx.y;
    const int pix0 = blockIdx.x * (64 * PIX) + wv * (16 * PIX);

    int soh[PIX], sow[PIX];
    const short* bp[PIX];
#pragma unroll
    for (int s = 0; s < PIX; ++s) {
        int pixs = pix0 + s * 16;
        soh[s] = pixs / 96;
        sow[s] = pixs - soh[s] * 96;
        bp[s] = xp + ((size_t)b * PHW + soh[s] * 98 + sow[s] + l15) * CINP + q * 8;
    }

    const int sco = tid >> 2, sqq = tid & 3;
    const short* wsrc = wb + (size_t)sco * (9 * CINP) + sqq * 8;

    f32x4 acc[PIX][4];
#pragma unroll
    for (int s = 0; s < PIX; ++s)
#pragma unroll
        for (int t = 0; t < 4; ++t) acc[s][t] = (f32x4){0.f, 0.f, 0.f, 0.f};

    for (int p = 0; p < KCH; ++p) {
        __syncthreads();
        bh8 wtmp[9];
#pragma unroll
        for (int tap = 0; tap < 9; ++tap)
            wtmp[tap] = *(const bh8*)(wsrc + tap * CINP + p * 32);
#pragma unroll
        for (int tap = 0; tap < 9; ++tap)
            *(bh8*)&smA[tap * 2048 + sco * 32 + sqq * 8] = wtmp[tap];
        __syncthreads();
#pragma unroll
        for (int tap = 0; tap < 9; ++tap) {
            const int ky = tap / 3, kx = tap - (tap / 3) * 3;
            bh8 bf[PIX];
#pragma unroll
            for (int s = 0; s < PIX; ++s)
                bf[s] = *(const bh8*)(bp[s] + (ky * 98 + kx) * CINP + p * 32);
#pragma unroll
            for (int t = 0; t < 4; ++t) {
                bh8 af = *(const bh8*)&smA[tap * 2048 + (t * 16 + l15) * 32 + q * 8];
#pragma unroll
                for (int s = 0; s < PIX; ++s)
                    acc[s][t] = __builtin_amdgcn_mfma_f32_16x16x32_bf16(
                        af, bf[s], acc[s][t], 0, 0, 0);
            }
        }
    }

#pragma unroll
    for (int s = 0; s < PIX; ++s) {
        size_t base = ((size_t)b * PHW + (soh[s] + 1) * 98 + sow[s] + l15 + 1) * 64;
#pragma unroll
        for (int t = 0; t < 4; ++t) {
            bh4 v4;
#pragma unroll
            for (int r = 0; r < 4; ++r) {
                int co = t * 16 + q * 4 + r;
                float v = acc[s][t][r] + bias[co];
                v = (v >= 0.f) ? v : 0.1f * v;
                v4[r] = f2bf(v);
            }
            *(bh4*)(o1 + base + t * 16 + q * 4) = v4;
        }
    }
}

// ---------------------------------------------------------------------------
// conv4 as tiled GEMM: block = 64 co x 192 pix (2 image rows), 18 k-chunks
// (tap x cin32). A[64co][32k] + B[192pix][32k] staged in LDS (pad-40 rows),
// wave = 48 pix x 64 co = 12 MFMA/chunk. Epilogue: offset-pair/mask writes.
// ---------------------------------------------------------------------------
__launch_bounds__(256)
__global__ void conv4_gemm(const short* __restrict__ xp,
                           const short* __restrict__ wb,
                           const float* __restrict__ bias,
                           float* __restrict__ offp,
                           short* __restrict__ maskb,
                           const float* __restrict__ flow1,
                           const float* __restrict__ flow2) {
    __shared__ __attribute__((aligned(16))) short smA[64 * 40];
    __shared__ __attribute__((aligned(16))) short smB[192 * 40];
    const int tid = threadIdx.x;
    const int lane = tid & 63, wv = tid >> 6;
    const int q = lane >> 4, l15 = lane & 15;
    const int pg = blockIdx.x;           // 48 row-pairs
    const int b = blockIdx.y;
    const int cob = blockIdx.z * 64;
    const int r0 = pg * 2;

    const int a_co = tid >> 2, a_ks = tid & 3;
    const short* asrc = wb + (size_t)(cob + a_co) * 576 + a_ks * 8;

    f32x4 acc[3][4];
#pragma unroll
    for (int pf = 0; pf < 3; ++pf)
#pragma unroll
        for (int cf = 0; cf < 4; ++cf) acc[pf][cf] = (f32x4){0.f, 0.f, 0.f, 0.f};

    for (int ch = 0; ch < 18; ++ch) {
        const int tap = ch >> 1, ci = (ch & 1) * 32;
        const int ky = tap / 3, kx = tap - (tap / 3) * 3;
        __syncthreads();
        *(bh8*)&smA[a_co * 40 + a_ks * 8] = *(const bh8*)(asrc + tap * 64 + ci);
#pragma unroll
        for (int it = 0; it < 3; ++it) {
            int id = it * 256 + tid;
            int sp = id >> 2, ks = id & 3;
            int srow = (sp >= 96) ? 1 : 0;
            int scol = sp - srow * 96;
            *(bh8*)&smB[sp * 40 + ks * 8] = *(const bh8*)&xp[
                ((size_t)b * PHW + (r0 + srow + ky) * 98 + scol + kx) * 64 + ci + ks * 8];
        }
        __syncthreads();
        bh8 bf[3], af[4];
#pragma unroll
        for (int pf = 0; pf < 3; ++pf)
            bf[pf] = *(const bh8*)&smB[(wv * 48 + pf * 16 + l15) * 40 + q * 8];
#pragma unroll
        for (int cf = 0; cf < 4; ++cf)
            af[cf] = *(const bh8*)&smA[(cf * 16 + l15) * 40 + q * 8];
#pragma unroll
        for (int pf = 0; pf < 3; ++pf)
#pragma unroll
            for (int cf = 0; cf < 4; ++cf)
                acc[pf][cf] = __builtin_amdgcn_mfma_f32_16x16x32_bf16(
                    af[cf], bf[pf], acc[pf][cf], 0, 0, 0);
    }

#pragma unroll
    for (int pf = 0; pf < 3; ++pf) {
        int local = wv * 48 + pf * 16 + l15;
        int lrow = (local >= 96) ? 1 : 0;
        int pix = (r0 + lrow) * 96 + (local - lrow * 96);
#pragma unroll
        for (int cf = 0; cf < 4; ++cf) {
#pragma unroll
            for (int r = 0; r < 4; ++r) {
                int chn = cob + cf * 16 + q * 4 + r;
                if (chn < 432) {
                    float v = acc[pf][cf][r] + bias[chn];
                    if (chn < 288) {
                        float tt = 10.f * tanhf(v);
                        const float* fl = (chn < 144) ? flow1 : flow2;
                        float fv = fl[(b * 2 + (1 - (chn & 1))) * HW + pix];
                        offp[(((size_t)b * 144 + (chn >> 1)) * HW + pix) * 2 + (chn & 1)] = tt + fv;
                    } else {
                        maskb[((size_t)b * 144 + (chn - 288)) * HW + pix] =
                            f2bf(1.f / (1.f + expf(-v)));
                    }
                }
            }
        }
    }
}

// ---------------------------------------------------------------------------
// Deform: group-planar xd, packed (dy,dx) pairs, XCD-swizzled blocks.
// ---------------------------------------------------------------------------
__global__ void deform_mfma(const short* __restrict__ xd,
                            const float* __restrict__ offp,
                            const short* __restrict__ maskb,
                            const short* __restrict__ wbd,
                            const float* __restrict__ bias,
                            float* __restrict__ out) {
    __shared__ float red[4][1024];
    const int tid = threadIdx.x;
    const int lane = tid & 63, wv = tid >> 6;
    const int q = lane >> 4, l15 = lane & 15;
    const int blk = blockIdx.x;
    const int xs = blk & 7, idx = blk >> 3;
    const int b = xs >> 1;                       // XCD-local batch
    const int pix0 = ((xs & 1) * 288 + idx) * 16;
    const int pix = pix0 + l15;
    const int h = pix / 96, w = pix - (pix / 96) * 96;

    const float* opp = offp + ((size_t)b * 144 * HW + pix) * 2;
    const short* mp = maskb + (size_t)b * 144 * HW + pix;
    const short* xb = xd + (size_t)b * 16 * HW * 8;
    const short* ap = wbd + (size_t)l15 * 1152 + wv * 288 + q * 8;

    // prefetch all offsets/masks for this lane's 9 (g,tap) slots
    f32x2 dxy[9];
    float mk[9];
#pragma unroll
    for (int i = 0; i < 9; ++i) {
        const int gt = wv * 36 + i * 4 + q;
        dxy[i] = *(const f32x2*)(opp + (size_t)gt * HW * 2);
        mk[i] = bf2f(mp[(size_t)gt * HW]);
    }

    f32x4 acc[4];
#pragma unroll
    for (int t = 0; t < 4; ++t) acc[t] = (f32x4){0.f, 0.f, 0.f, 0.f};

#pragma unroll
    for (int i = 0; i < 9; ++i) {
        const int gt = wv * 36 + i * 4 + q;
        const int g = gt / 9, tap = gt - (gt / 9) * 9;
        float py = dxy[i][0] + (float)(tap / 3) + (float)h - 1.f;
        float px = dxy[i][1] + (float)(tap - (tap / 3) * 3) + (float)w - 1.f;
        float y0f = floorf(py), x0f = floorf(px);
        float wy1 = py - y0f, wx1 = px - x0f;
        float wy0 = 1.f - wy1, wx0 = 1.f - wx1;
        int y0 = (int)y0f, x0 = (int)x0f;
        int y1 = y0 + 1, x1 = x0 + 1;
        bool vy0 = (y0 >= 0) && (y0 < Hh), vy1 = (y1 >= 0) && (y1 < Hh);
        bool vx0 = (x0 >= 0) && (x0 < Ww), vx1 = (x1 >= 0) && (x1 < Ww);
        int cy0 = min(max(y0, 0), Hh - 1), cy1 = min(max(y1, 0), Hh - 1);
        int cx0 = min(max(x0, 0), Ww - 1), cx1 = min(max(x1, 0), Ww - 1);
        float m = mk[i];
        float w00 = wy0 * wx0 * ((vy0 && vx0) ? m : 0.f);
        float w01 = wy0 * wx1 * ((vy0 && vx1) ? m : 0.f);
        float w10 = wy1 * wx0 * ((vy1 && vx0) ? m : 0.f);
        float w11 = wy1 * wx1 * ((vy1 && vx1) ? m : 0.f);
        const short* cb = xb + (size_t)g * HW * 8;
        bh8 a00 = *(const bh8*)(cb + (size_t)(cy0 * 96 + cx0) * 8);
        bh8 a01 = *(const bh8*)(cb + (size_t)(cy0 * 96 + cx1) * 8);
        bh8 a10 = *(const bh8*)(cb + (size_t)(cy1 * 96 + cx0) * 8);
        bh8 a11 = *(const bh8*)(cb + (size_t)(cy1 * 96 + cx1) * 8);
        bh8 bf;
#pragma unroll
        for (int c = 0; c < 8; ++c) {
            float s = w00 * bf2f(a00[c]) + w01 * bf2f(a01[c])
                    + w10 * bf2f(a10[c]) + w11 * bf2f(a11[c]);
            bf[c] = f2bf(s);
        }
#pragma unroll
        for (int t = 0; t < 4; ++t) {
            bh8 af = *(const bh8*)(ap + (size_t)t * 16 * 1152 + i * 32);
            acc[t] = __builtin_amdgcn_mfma_f32_16x16x32_bf16(af, bf, acc[t], 0, 0, 0);
        }
    }

#pragma unroll
    for (int t = 0; t < 4; ++t)
#pragma unroll
        for (int r = 0; r < 4; ++r)
            red[wv][(t * 16 + q * 4 + r) * 16 + l15] = acc[t][r];
    __syncthreads();
    for (int e = tid; e < 1024; e += 256) {
        int co = e >> 4, pl = e & 15;
        float v = red[0][e] + red[1][e] + red[2][e] + red[3][e] + bias[co];
        out[((size_t)b * 64 + co) * HW + pix0 + pl] = v;
    }
}

// ---------------------------------------------------------------------------
extern "C" void kernel_launch(void* const* d_in, const int* in_sizes, int n_in,
                              void* d_out, int out_size, void* d_ws, size_t ws_size,
                              hipStream_t stream) {
    const float* x      = (const float*)d_in[0];
    const float* extra  = (const float*)d_in[1];
    const float* flow1  = (const float*)d_in[2];
    const float* flow2  = (const float*)d_in[3];
    const float* weight = (const float*)d_in[4];
    const float* bias   = (const float*)d_in[5];
    const float* ow0    = (const float*)d_in[6];
    const float* ob0    = (const float*)d_in[7];
    const float* ow1    = (const float*)d_in[8];
    const float* ob1    = (const float*)d_in[9];
    const float* ow2    = (const float*)d_in[10];
    const float* ob2    = (const float*)d_in[11];
    const float* ow3    = (const float*)d_in[12];
    const float* ob3    = (const float*)d_in[13];
    float* out = (float*)d_out;

    char* wsb = (char*)d_ws;
    short* xpad1 = (short*)wsb;   wsb += (size_t)4 * PHW * 224 * 2;
    short* hpa   = (short*)wsb;   wsb += (size_t)4 * PHW * 64 * 2;
    short* hpb   = (short*)wsb;   wsb += (size_t)4 * PHW * 64 * 2;
    float* offpair = (float*)wsb; wsb += (size_t)4 * 144 * HW * 2 * 4;
    short* maskbuf = (short*)wsb; wsb += (size_t)4 * 144 * HW * 2;
    short* xd      = (short*)wsb; wsb += (size_t)4 * 16 * HW * 8 * 2 + 32;
    short* wb0     = (short*)wsb; wsb += 64 * 9 * 224 * 2;
    short* wb1     = (short*)wsb; wsb += 64 * 9 * 64 * 2;
    short* wb2     = (short*)wsb; wsb += 64 * 9 * 64 * 2;
    short* wb3     = (short*)wsb; wsb += 448 * 9 * 64 * 2;
    short* wbd     = (short*)wsb;

    auto g1 = [](int n) { return dim3((n + 255) / 256); };
    zero_borders<<<g1(4 * 388 * 352), 256, 0, stream>>>(xpad1, hpa, hpb);
    pack_x1<<<dim3(288, 7, 4), 256, 0, stream>>>(extra, flow1, flow2, xpad1);
    pack_xd<<<dim3(288, 4, 4), 256, 0, stream>>>(x, xd);
    prep_weights<<<g1(534528), 256, 0, stream>>>(ow0, ow1, ow2, ow3, weight,
                                                 wb0, wb1, wb2, wb3, wbd);

    conv_mfma<224, 7, 1><<<dim3(144, 4), 256, 0, stream>>>(xpad1, wb0, ob0, hpa);
    conv_mfma<64, 2, 1><<<dim3(144, 4), 256, 0, stream>>>(hpa, wb1, ob1, hpb);
    conv_mfma<64, 2, 1><<<dim3(144, 4), 256, 0, stream>>>(hpb, wb2, ob2, hpa);
    conv4_gemm<<<dim3(48, 4, 7), 256, 0, stream>>>(hpa, wb3, ob3, offpair,
                                                   maskbuf, flow1, flow2);
    deform_mfma<<<dim3(2304), 256, 0, stream>>>(xd, offpair, maskbuf, wbd, bias, out);
}